// Round 7
// baseline (126.073 us; speedup 1.0000x reference)
//
#include <hip/hip_runtime.h>
#include <hip/hip_bf16.h>
#include <stdint.h>

typedef float  f32x4  __attribute__((ext_vector_type(4)));
typedef short  bf16x8 __attribute__((ext_vector_type(8)));

#define C_IN   384
#define C_OUT  384
#define Hdim   56
#define Wdim   56
#define HWsz   3136
#define KC     32
#define NCHUNK 12
#define NOSUB  24
#define NBLK   (Hdim * 32)    // 1792, %8 == 0

__device__ __forceinline__ short f2bf(float f) {
    union { float f; uint32_t u; } v; v.f = f;
    uint32_t u = v.u + (0x7FFFu + ((v.u >> 16) & 1u));   // RNE
    return (short)(u >> 16);
}

// ---------------- W prepack: B-fragment order bf16 ----------------
// flat idx = ((cblk*24 + osub)*64 + lane)*8 + j
// value    = bf16( w_pw[ (osub*16 + (lane&15)) * 384 + cblk*32 + (lane>>4)*8 + j ] )
// Read as B-operand fragment: B[k = c][col = o].
__global__ void prep_w_kernel(const float* __restrict__ wpw, short* __restrict__ apre) {
    int idx = blockIdx.x * 256 + threadIdx.x;
    if (idx >= C_OUT * C_IN) return;
    int j    = idx & 7;
    int lane = (idx >> 3) & 63;
    int osub = (idx >> 9) % NOSUB;
    int cblk = idx / (NOSUB * 512);
    int o = osub * 16 + (lane & 15);
    int c = cblk * KC + (lane >> 4) * 8 + j;
    apre[idx] = f2bf(wpw[o * C_IN + c]);
}

// ---------------- Fused v3: one block per (n,h); ONE barrier ----------------
// Phase 1: all 384 dw channels -> LDS [pix 64][c 384] bf16 (XOR-swizzled 16B units).
//          Wave w computes channels [48w, 48w+48) in 6 groups of 8, reg-dbuf loads.
// Phase 2: 12 MFMA chunks, A(dw tile) from LDS, B(W) from L2-resident prepack.
//          Swapped operands -> D[pix][o] -> f32x4 stores of 4 consecutive pixels.
__global__ __launch_bounds__(512, 4) void fused3_kernel(
    const float* __restrict__ x, const float* __restrict__ wdw,
    const short* __restrict__ apre, float* __restrict__ y) {

    __shared__ __align__(16) short Bt[64 * 384];   // 48 KB

    // XCD-chunked bijective swizzle: contiguous (n,h) range per XCD
    const int p = (int)blockIdx.x;
    const int l = (p & 7) * (NBLK / 8) + (p >> 3);
    const int h = l % Hdim;
    const int n = l / Hdim;

    const int wave = (int)threadIdx.x >> 6;
    const int lane = (int)threadIdx.x & 63;
    const int col  = lane & 15;
    const int kb   = lane >> 4;

    const float* xn = x + (size_t)n * C_IN * HWsz;

    // ================= Phase 1: depthwise =================
    // group g: channels c0 = wave*48 + g*8; lane = pixel; 16B unit u = wave*6+g
    auto loadx = [&](float (&v)[8][3], int g) {
        const int c0 = __builtin_amdgcn_readfirstlane(wave * 48 + g * 8);
        const float* xc = xn + (size_t)c0 * HWsz;
#pragma unroll
        for (int q = 0; q < 8; ++q)
#pragma unroll
            for (int d = 0; d < 3; ++d) {
                const int hh = h + d - 1;
                const bool ok = (hh >= 0) && (hh < Hdim) && (lane < Wdim);
                v[q][d] = ok ? xc[(size_t)q * HWsz + hh * Wdim + lane] : 0.f;
            }
    };

    auto dwbody = [&](float (&vc)[8][3], int g) {
        const int c0 = __builtin_amdgcn_readfirstlane(wave * 48 + g * 8);
        const float* wp = wdw + c0 * 9;
        float wk[8][9];
#pragma unroll
        for (int q = 0; q < 8; ++q)
#pragma unroll
            for (int t = 0; t < 9; ++t) wk[q][t] = wp[q * 9 + t];

        bf16x8 pk;
#pragma unroll
        for (int q = 0; q < 8; ++q) {
            float a = 0.f;
#pragma unroll
            for (int d = 0; d < 3; ++d) {
                const float c_ = vc[q][d];
                float lf = __shfl_up(c_, 1);
                if (lane == 0) lf = 0.f;
                const float rt = __shfl_down(c_, 1);  // lane55 pulls lane56 == 0
                a = fmaf(wk[q][d * 3 + 0], lf, a);
                a = fmaf(wk[q][d * 3 + 1], c_, a);
                a = fmaf(wk[q][d * 3 + 2], rt, a);
            }
            pk[q] = f2bf(a);
        }
        const int u  = wave * 6 + g;
        const int up = (u & ~7) | ((u & 7) ^ (lane & 7));
        *reinterpret_cast<bf16x8*>(&Bt[lane * 384 + up * 8]) = pk;
    };

    {
        float v0[8][3], v1[8][3];
        loadx(v0, 0);
#pragma unroll
        for (int g = 0; g < 6; g += 2) {
            if (g + 1 < 6) loadx(v1, g + 1);
            dwbody(v0, g);
            if (g + 2 < 6) loadx(v0, g + 2);
            if (g + 1 < 6) dwbody(v1, g + 1);
        }
    }

    __syncthreads();   // the ONLY barrier

    // ================= Phase 2: GEMM =================
    f32x4 acc[3][4];
#pragma unroll
    for (int m = 0; m < 3; ++m)
#pragma unroll
        for (int q = 0; q < 4; ++q) acc[m][q] = (f32x4)0.f;

    const int px7 = col & 7;   // pix & 7 (q*16 ≡ 0 mod 8)

#pragma unroll
    for (int ch = 0; ch < NCHUNK; ++ch) {
        // B-operand (W) fragments: L2/L3-resident prepack
        bf16x8 wf[3];
#pragma unroll
        for (int m = 0; m < 3; ++m)
            wf[m] = *reinterpret_cast<const bf16x8*>(
                apre + (((ch * NOSUB + wave * 3 + m) * 64 + lane) << 3));

        // A-operand (dw) fragments from LDS: pix = q*16+col, k-unit u = ch*4+kb
        bf16x8 dfr[4];
        const int u  = ch * 4 + kb;
#pragma unroll
        for (int q = 0; q < 4; ++q) {
            const int pix = q * 16 + col;
            const int up  = (u & ~7) | ((u & 7) ^ px7);
            dfr[q] = *reinterpret_cast<const bf16x8*>(&Bt[pix * 384 + up * 8]);
        }

#pragma unroll
        for (int m = 0; m < 3; ++m)
#pragma unroll
            for (int q = 0; q < 4; ++q)
                acc[m][q] = __builtin_amdgcn_mfma_f32_16x16x32_bf16(
                    dfr[q], wf[m], acc[m][q], 0, 0, 0);   // D[pix][o]
    }

    // ---- epilogue: lane holds 4 consecutive pixels (kb*4+r) at o = osub*16+col ----
#pragma unroll
    for (int m = 0; m < 3; ++m) {
        const int o = (wave * 3 + m) * 16 + col;
        float* yo = y + ((size_t)(n * C_OUT + o)) * HWsz + h * Wdim;
#pragma unroll
        for (int q = 0; q < 4; ++q) {
            const int pix0 = q * 16 + kb * 4;
            if (pix0 < Wdim)
                *reinterpret_cast<f32x4*>(yo + pix0) = acc[m][q];
        }
    }
}

extern "C" void kernel_launch(void* const* d_in, const int* in_sizes, int n_in,
                              void* d_out, int out_size, void* d_ws, size_t ws_size,
                              hipStream_t stream) {
    const float* x   = (const float*)d_in[0];
    const float* wdw = (const float*)d_in[1];
    const float* wpw = (const float*)d_in[2];
    float* y = (float*)d_out;
    short* apre = (short*)d_ws;   // 294912 B

    hipLaunchKernelGGL(prep_w_kernel, dim3((C_OUT * C_IN + 255) / 256), dim3(256),
                       0, stream, wpw, apre);
    hipLaunchKernelGGL(fused3_kernel, dim3(NBLK), dim3(512),
                       0, stream, x, wdw, apre, y);
}